// Round 9
// baseline (127.777 us; speedup 1.0000x reference)
//
#include <hip/hip_runtime.h>
#include <hip/hip_bf16.h>
#include <cstdint>
#include <cstddef>

#define BATCH 32
#define CH    256
#define NSP   4096               // 64*64 spatial
#define RED   64                 // CH / 4
#define GAMMA 0.5f
#define NSPLIT 4                 // split-K factor
#define KSEG  (NSP / NSPLIT)     // 1024
#define NKT   (KSEG / 64)        // 16 K-iters of BK=64 (even)
#define GTILE (CH * CH)          // 65536 elems per (s,b) Gram tile
#define SLICE_STRIDE ((size_t)BATCH * GTILE)   // elems per split slice

typedef float f32x4 __attribute__((ext_vector_type(4)));
typedef short short8 __attribute__((ext_vector_type(8)));

static __device__ inline unsigned short bfu(float f) {
  __hip_bfloat16 h = __float2bfloat16(f);   // RNE
  return __builtin_bit_cast(unsigned short, h);
}

// stage 8 f32x4 rows (bf16-converted, XOR-swizzled) into an LDS panel
static __device__ __forceinline__ void stage_panel(char* cP, const f32x4* pa,
                                                   int rsub, int c4) {
#pragma unroll
  for (int i = 0; i < 8; ++i) {
    int row = i * 32 + rsub;
    int byte = row * 128 + c4 * 8;
    byte ^= (row & 7) << 4;
    uint64_t w = (uint64_t)bfu(pa[i][0]) | ((uint64_t)bfu(pa[i][1]) << 16) |
                 ((uint64_t)bfu(pa[i][2]) << 32) | ((uint64_t)bfu(pa[i][3]) << 48);
    *reinterpret_cast<uint64_t*>(cP + byte) = w;
  }
}

// load one K-slab (8 rows of f32x4 per thread) into registers
static __device__ __forceinline__ void load_slab(f32x4* pa, const float* base,
                                                 int rsub, int c4) {
#pragma unroll
  for (int i = 0; i < 8; ++i) {
    int row = i * 32 + rsub;
    pa[i] = *reinterpret_cast<const f32x4*>(base + (size_t)row * NSP + c4 * 4);
  }
}

// fragments + MFMA from one LDS panel (feeds BOTH operands, symmetric Gram)
static __device__ __forceinline__ void compute_panel(const char* cP, f32x4 acc[2][4],
                                                     int wave, int q, int lane) {
#pragma unroll
  for (int kh = 0; kh < 2; ++kh) {
    short8 af[2];
#pragma unroll
    for (int m = 0; m < 2; ++m) {
      int rowa = wave * 32 + m * 16 + (lane & 15);
      int bytea = rowa * 128 + kh * 64 + ((lane >> 4) * 16);
      bytea ^= (rowa & 7) << 4;
      af[m] = *reinterpret_cast<const short8*>(cP + bytea);
    }
#pragma unroll
    for (int n = 0; n < 4; ++n) {
      int rowb = q * 64 + n * 16 + (lane & 15);
      int byteb = rowb * 128 + kh * 64 + ((lane >> 4) * 16);
      byteb ^= (rowb & 7) << 4;
      short8 bf = *reinterpret_cast<const short8*>(cP + byteb);
#pragma unroll
      for (int m = 0; m < 2; ++m)
        acc[m][n] = __builtin_amdgcn_mfma_f32_16x16x32_bf16(
            af[m], bf, acc[m][n], 0, 0, 0);
    }
  }
}

// ---------------------------------------------------------------------------
// K1: symmetric Gram, column-quartered, LDS double-buffered (1 barrier/K-step)
//     with 2-deep even/odd register prefetch. grid = 32 b * 4 s * 4 q = 512
//     blocks (2/CU), 512 threads (8 waves x 32-row strips). Block computes a
//     256x64 slice of the (b,s) 256x256 partial Gram; the 256-row K-slab
//     panel is staged once and feeds both operands. gpart[s][b][256][256] f32.
// ---------------------------------------------------------------------------
__global__ __launch_bounds__(512, 4)   // 4 waves/EU min = 2 blocks/CU
void gram_sym_kernel(const float* __restrict__ x, float* __restrict__ gpart) {
  const int bx   = blockIdx.x;      // 0..511
  const int xcd  = bx & 7;
  const int slot = bx >> 3;         // 0..63 within XCD
  const int g_   = xcd * 16 + (slot >> 2);   // (b,s) group 0..127
  const int q    = slot & 3;        // column quarter
  const int b    = g_ >> 2;
  const int s    = g_ & 3;
  const int tid  = threadIdx.x;
  const int lane = tid & 63;
  const int wave = tid >> 6;        // 0..7 -> 32-row strip

  __shared__ unsigned short lds0[256 * 64];   // 32 KiB each, XOR-swizzled bf16
  __shared__ unsigned short lds1[256 * 64];

  const int rsub = tid >> 4;        // 0..31 (staging row within 32-row group)
  const int c4   = tid & 15;        // f32x4 column chunk (64 floats per row)

  const float* base = x + (size_t)b * CH * NSP + (size_t)s * KSEG;

  f32x4 pa0[8], pa1[8];
  f32x4 acc[2][4];
#pragma unroll
  for (int m = 0; m < 2; ++m)
#pragma unroll
    for (int n = 0; n < 4; ++n)
      acc[m][n] = (f32x4){0.f, 0.f, 0.f, 0.f};

  char* cL0 = (char*)lds0;
  char* cL1 = (char*)lds1;

  // prologue: tiles 0,1 in flight; stage tile 0; prefetch tile 2
  load_slab(pa0, base, rsub, c4);            // tile 0
  load_slab(pa1, base + 64, rsub, c4);       // tile 1
  stage_panel(cL0, pa0, rsub, c4);           // waits pa0
  load_slab(pa0, base + 2 * 64, rsub, c4);   // tile 2
  __syncthreads();                           // lds0 ready

#pragma unroll 1
  for (int kt = 0; kt < NKT; kt += 2) {
    // phase A: compute lds0 (tile kt), stage lds1 (tile kt+1), prefetch kt+3
    stage_panel(cL1, pa1, rsub, c4);                       // waits pa1
    if (kt + 3 < NKT) load_slab(pa1, base + (kt + 3) * 64, rsub, c4);
    compute_panel(cL0, acc, wave, q, lane);
    __syncthreads();                                       // lds1 ready, lds0 free

    // phase B: compute lds1 (tile kt+1), stage lds0 (tile kt+2), prefetch kt+4
    if (kt + 2 < NKT) {
      stage_panel(cL0, pa0, rsub, c4);                     // waits pa0
      if (kt + 4 < NKT) load_slab(pa0, base + (kt + 4) * 64, rsub, c4);
    }
    compute_panel(cL1, acc, wave, q, lane);
    __syncthreads();                                       // lds0 ready, lds1 free
  }

  // ---- store f32 slice: 16 consecutive lanes -> 64 contiguous bytes ----
  float* g = gpart + ((size_t)s * BATCH + b) * GTILE;
#pragma unroll
  for (int m = 0; m < 2; ++m)
#pragma unroll
    for (int n = 0; n < 4; ++n)
#pragma unroll
      for (int r = 0; r < 4; ++r) {
        int row = wave * 32 + m * 16 + ((lane >> 4) * 4 + r);
        int col = q * 64 + n * 16 + (lane & 15);
        g[(size_t)row * CH + col] = acc[m][n][r];
      }
}

// ---------------------------------------------------------------------------
// K2: density. grid = 32 b * 8 row-groups = 256 blocks, 256 threads (4 waves,
//     8 rows/wave). sq from the Gram diagonal summed in split order (exact
//     cancellation on the diagonal). f32x4 loads: 1 KB/wave coalesced.
// ---------------------------------------------------------------------------
__global__ __launch_bounds__(256)
void density_kernel(const float* __restrict__ gpart, float* __restrict__ density) {
  const int blk  = blockIdx.x;   // 0..255
  const int b    = blk >> 3;
  const int rg   = blk & 7;      // 32-row group
  const int t    = threadIdx.x;
  const int lane = t & 63;
  const int wave = t >> 6;       // 0..3

  __shared__ float sq[CH];
  {
    size_t off = (size_t)b * GTILE + (size_t)t * (CH + 1);   // diagonal
    float v = 0.f;
#pragma unroll
    for (int s = 0; s < NSPLIT; ++s) v += gpart[off + (size_t)s * SLICE_STRIDE];
    sq[t] = v;
  }
  __syncthreads();

  const float* gb = gpart + (size_t)b * GTILE;
#pragma unroll 1
  for (int rr = 0; rr < 8; ++rr) {
    int r = rg * 32 + wave * 8 + rr;
    float sqr = sq[r];
    size_t off = (size_t)r * CH + lane * 4;
    f32x4 g = (f32x4){0.f, 0.f, 0.f, 0.f};
#pragma unroll
    for (int s = 0; s < NSPLIT; ++s)
      g += *reinterpret_cast<const f32x4*>(gb + off + (size_t)s * SLICE_STRIDE);
    float ssum = 0.f;
#pragma unroll
    for (int k = 0; k < 4; ++k) {
      float d2 = fmaxf(sqr + sq[lane * 4 + k] - 2.f * g[k], 0.f);
      ssum += __expf(-0.5f * d2);
    }
    ssum += __shfl_xor(ssum, 1);
    ssum += __shfl_xor(ssum, 2);
    ssum += __shfl_xor(ssum, 4);
    ssum += __shfl_xor(ssum, 8);
    ssum += __shfl_xor(ssum, 16);
    ssum += __shfl_xor(ssum, 32);
    if (lane == 0) density[b * CH + r] = ssum * (1.0f / CH);
  }
}

// ---------------------------------------------------------------------------
// K3: per-batch MLP  scale = sigmoid(relu(density@W1+b1)@W2+b2) + GAMMA
// ---------------------------------------------------------------------------
__global__ __launch_bounds__(256)
void mlp_kernel(const float* __restrict__ density,
                const float* __restrict__ w1, const float* __restrict__ b1,
                const float* __restrict__ w2, const float* __restrict__ b2,
                float* __restrict__ scale) {
  const int b = blockIdx.x;
  const int t = threadIdx.x;
  __shared__ float dens[CH];
  __shared__ float hid[RED];
  dens[t] = density[b * CH + t];
  __syncthreads();
  if (t < RED) {
    float s = b1[t];
#pragma unroll 4
    for (int c = 0; c < CH; ++c) s += dens[c] * w1[c * RED + t];
    hid[t] = fmaxf(s, 0.f);
  }
  __syncthreads();
  float s = b2[t];
#pragma unroll
  for (int h = 0; h < RED; ++h) s += hid[h] * w2[h * CH + t];
  scale[b * CH + t] = 1.f / (1.f + __expf(-s)) + GAMMA;
}

// ---------------------------------------------------------------------------
// K4: out = x * scale[b,c]   (float4 grid-stride, nontemporal stores)
// ---------------------------------------------------------------------------
__global__ __launch_bounds__(256)
void scale_kernel(const f32x4* __restrict__ x, const float* __restrict__ scale,
                  f32x4* __restrict__ out, int n4) {
  const int stride = gridDim.x * blockDim.x;
  for (int i = blockIdx.x * blockDim.x + threadIdx.x; i < n4; i += stride) {
    float s = scale[i >> 10];          // 1024 float4 per (b,c) row
    __builtin_nontemporal_store(x[i] * s, &out[i]);
  }
}

extern "C" void kernel_launch(void* const* d_in, const int* in_sizes, int n_in,
                              void* d_out, int out_size, void* d_ws, size_t ws_size,
                              hipStream_t stream) {
  const float* x  = (const float*)d_in[0];
  const float* w1 = (const float*)d_in[1];
  const float* b1 = (const float*)d_in[2];
  const float* w2 = (const float*)d_in[3];
  const float* b2 = (const float*)d_in[4];
  float* out = (float*)d_out;

  float* gpart   = (float*)d_ws;                       // 4*32*65536 f32 = 33.6 MB
  float* density = gpart + NSPLIT * SLICE_STRIDE;      // 32*256
  float* scale   = density + BATCH * CH;               // 32*256

  gram_sym_kernel<<<dim3(512), dim3(512), 0, stream>>>(x, gpart);
  density_kernel<<<dim3(BATCH * 8), dim3(256), 0, stream>>>(gpart, density);
  mlp_kernel<<<dim3(BATCH), dim3(256), 0, stream>>>(density, w1, b1, w2, b2, scale);

  const int n4 = BATCH * CH * NSP / 4;
  scale_kernel<<<dim3(4096), dim3(256), 0, stream>>>(
      (const f32x4*)x, scale, (f32x4*)out, n4);
}

// Round 11
// 110.773 us; speedup vs baseline: 1.1535x; 1.1535x over previous
//
#include <hip/hip_runtime.h>
#include <hip/hip_bf16.h>
#include <cstdint>
#include <cstddef>

#define BATCH 32
#define CH    256
#define NSP   4096               // 64*64 spatial
#define RED   64                 // CH / 4
#define GAMMA 0.5f
#define NSPLIT 4                 // split-K factor
#define KSEG  (NSP / NSPLIT)     // 1024
#define BK    32                 // K per LDS tile (f32)
#define NKT   (KSEG / BK)        // 32 K-iters
#define GTILE (CH * CH)          // 65536 elems per (s,b) Gram tile
#define SLICE_STRIDE ((size_t)BATCH * GTILE)   // elems per split slice

typedef float f32x4 __attribute__((ext_vector_type(4)));
typedef short short8 __attribute__((ext_vector_type(8)));

static __device__ inline unsigned short bfu(float f) {
  __hip_bfloat16 h = __float2bfloat16(f);   // RNE
  return __builtin_bit_cast(unsigned short, h);
}

// pack 8 f32 (two f32x4) -> short8 bf16 fragment
static __device__ __forceinline__ short8 pack8(f32x4 lo, f32x4 hi) {
  short8 r;
  r[0] = (short)bfu(lo[0]); r[1] = (short)bfu(lo[1]);
  r[2] = (short)bfu(lo[2]); r[3] = (short)bfu(lo[3]);
  r[4] = (short)bfu(hi[0]); r[5] = (short)bfu(hi[1]);
  r[6] = (short)bfu(hi[2]); r[7] = (short)bfu(hi[3]);
  return r;
}

// ---------------------------------------------------------------------------
// K1: symmetric Gram, column-quartered, ASYNC global_load_lds staging with
//     counted vmcnt (loads stay in flight across barriers). grid = 32 b *
//     4 s * 4 q = 512 blocks (2/CU), 512 threads (8 waves x 32-row strips).
//     LDS: two f32 panels [256][BK=32] (32 KiB each), linear dest; the
//     GLOBAL source address carries the XOR swizzle (granule ^= row&7) so
//     fragment ds_reads are conflict-free. f32->bf16 conversion happens at
//     fragment-read time (VALU has headroom). gpart[s][b][256][256] f32.
// ---------------------------------------------------------------------------
__global__ __launch_bounds__(512, 4)   // 4 waves/EU min = 2 blocks/CU
void gram_sym_kernel(const float* __restrict__ x, float* __restrict__ gpart) {
  const int bx   = blockIdx.x;      // 0..511
  const int xcd  = bx & 7;
  const int slot = bx >> 3;         // 0..63 within XCD
  const int g_   = xcd * 16 + (slot >> 2);   // (b,s) group 0..127
  const int q    = slot & 3;        // column quarter
  const int b    = g_ >> 2;
  const int s    = g_ & 3;
  const int tid  = threadIdx.x;
  const int lane = tid & 63;
  const int wave = tid >> 6;        // 0..7 -> 32-row strip

  __shared__ float lds0[256 * BK];  // 32 KiB
  __shared__ float lds1[256 * BK];  // 32 KiB

  const float* xb = x + (size_t)b * CH * NSP + (size_t)s * KSEG;

  // ---- staging addressing (per-thread source, wave-uniform LDS dest) ----
  // issue j (0..3) of wave w covers LDS granules (w*4+j)*64 + lane
  // granule G -> row = G>>3, slot = G&7 ; source granule = slot ^ (row&7)
  // row = (w*4+j)*8 + (lane>>3); row&7 == lane>>3  =>
  // source granule = (lane&7) ^ (lane>>3)   (independent of w,j)
  const int srow  = lane >> 3;                    // 0..7
  const int sgran = (lane & 7) ^ srow;            // swizzled source granule
  const float* src[4];
#pragma unroll
  for (int j = 0; j < 4; ++j) {
    int chan = wave * 32 + j * 8 + srow;
    src[j] = xb + (size_t)chan * NSP + sgran * 4;
  }
  float* lb0[4]; float* lb1[4];
#pragma unroll
  for (int j = 0; j < 4; ++j) {
    lb0[j] = lds0 + (wave * 4 + j) * 256;         // 1 KiB per issue
    lb1[j] = lds1 + (wave * 4 + j) * 256;
  }

  f32x4 acc[2][4];
#pragma unroll
  for (int m = 0; m < 2; ++m)
#pragma unroll
    for (int n = 0; n < 4; ++n)
      acc[m][n] = (f32x4){0.f, 0.f, 0.f, 0.f};

  // fragment read helper data
  const int g0byte = ((lane >> 4) * 2) << 4;      // granule g0 * 16 bytes
  const int rl     = lane & 15;

  // ---- prologue: stage tile 0 into lds0 ----
#pragma unroll
  for (int j = 0; j < 4; ++j)
    __builtin_amdgcn_global_load_lds(
        (const __attribute__((address_space(1))) unsigned int*)(src[j]),
        (__attribute__((address_space(3))) unsigned int*)(lb0[j]), 16, 0, 0);

#pragma unroll 1
  for (int t = 0; t < NKT; ++t) {
    // ---- issue next tile's stage (stays in flight across the barrier) ----
    if (t + 1 < NKT) {
      const int koff = (t + 1) * BK;
      if ((t + 1) & 1) {
#pragma unroll
        for (int j = 0; j < 4; ++j)
          __builtin_amdgcn_global_load_lds(
              (const __attribute__((address_space(1))) unsigned int*)(src[j] + koff),
              (__attribute__((address_space(3))) unsigned int*)(lb1[j]), 16, 0, 0);
      } else {
#pragma unroll
        for (int j = 0; j < 4; ++j)
          __builtin_amdgcn_global_load_lds(
              (const __attribute__((address_space(1))) unsigned int*)(src[j] + koff),
              (__attribute__((address_space(3))) unsigned int*)(lb0[j]), 16, 0, 0);
      }
      asm volatile("s_waitcnt vmcnt(4)" ::: "memory");   // current tile landed
    } else {
      asm volatile("s_waitcnt vmcnt(0)" ::: "memory");
    }
    __builtin_amdgcn_sched_barrier(0);
    __builtin_amdgcn_s_barrier();

    // ---- compute current tile: frags (f32->bf16) + MFMA ----
    const char* cP = (t & 1) ? (const char*)lds1 : (const char*)lds0;
    short8 af[2];
#pragma unroll
    for (int m = 0; m < 2; ++m) {
      int rowa = wave * 32 + m * 16 + rl;
      int b1 = rowa * 128 + (g0byte ^ ((rowa & 7) << 4));
      f32x4 lo = *reinterpret_cast<const f32x4*>(cP + b1);
      f32x4 hi = *reinterpret_cast<const f32x4*>(cP + (b1 ^ 16));
      af[m] = pack8(lo, hi);
    }
#pragma unroll
    for (int n = 0; n < 4; ++n) {
      int rowb = q * 64 + n * 16 + rl;
      int b1 = rowb * 128 + (g0byte ^ ((rowb & 7) << 4));
      f32x4 lo = *reinterpret_cast<const f32x4*>(cP + b1);
      f32x4 hi = *reinterpret_cast<const f32x4*>(cP + (b1 ^ 16));
      short8 bf = pack8(lo, hi);
#pragma unroll
      for (int m = 0; m < 2; ++m)
        acc[m][n] = __builtin_amdgcn_mfma_f32_16x16x32_bf16(
            af[m], bf, acc[m][n], 0, 0, 0);
    }
    __builtin_amdgcn_s_barrier();   // all waves done reading before overwrite
  }

  // ---- store f32 slice: 16 consecutive lanes -> 64 contiguous bytes ----
  float* g = gpart + ((size_t)s * BATCH + b) * GTILE;
#pragma unroll
  for (int m = 0; m < 2; ++m)
#pragma unroll
    for (int n = 0; n < 4; ++n)
#pragma unroll
      for (int r = 0; r < 4; ++r) {
        int row = wave * 32 + m * 16 + ((lane >> 4) * 4 + r);
        int col = q * 64 + n * 16 + rl;
        g[(size_t)row * CH + col] = acc[m][n][r];
      }
}

// ---------------------------------------------------------------------------
// K2: density. grid = 32 b * 8 row-groups = 256 blocks, 256 threads (4 waves,
//     8 rows/wave). sq from the Gram diagonal summed in split order (exact
//     cancellation on the diagonal). f32x4 loads: 1 KB/wave coalesced.
// ---------------------------------------------------------------------------
__global__ __launch_bounds__(256)
void density_kernel(const float* __restrict__ gpart, float* __restrict__ density) {
  const int blk  = blockIdx.x;   // 0..255
  const int b    = blk >> 3;
  const int rg   = blk & 7;      // 32-row group
  const int t    = threadIdx.x;
  const int lane = t & 63;
  const int wave = t >> 6;       // 0..3

  __shared__ float sq[CH];
  {
    size_t off = (size_t)b * GTILE + (size_t)t * (CH + 1);   // diagonal
    float v = 0.f;
#pragma unroll
    for (int s = 0; s < NSPLIT; ++s) v += gpart[off + (size_t)s * SLICE_STRIDE];
    sq[t] = v;
  }
  __syncthreads();

  const float* gb = gpart + (size_t)b * GTILE;
#pragma unroll 1
  for (int rr = 0; rr < 8; ++rr) {
    int r = rg * 32 + wave * 8 + rr;
    float sqr = sq[r];
    size_t off = (size_t)r * CH + lane * 4;
    f32x4 g = (f32x4){0.f, 0.f, 0.f, 0.f};
#pragma unroll
    for (int s = 0; s < NSPLIT; ++s)
      g += *reinterpret_cast<const f32x4*>(gb + off + (size_t)s * SLICE_STRIDE);
    float ssum = 0.f;
#pragma unroll
    for (int k = 0; k < 4; ++k) {
      float d2 = fmaxf(sqr + sq[lane * 4 + k] - 2.f * g[k], 0.f);
      ssum += __expf(-0.5f * d2);
    }
    ssum += __shfl_xor(ssum, 1);
    ssum += __shfl_xor(ssum, 2);
    ssum += __shfl_xor(ssum, 4);
    ssum += __shfl_xor(ssum, 8);
    ssum += __shfl_xor(ssum, 16);
    ssum += __shfl_xor(ssum, 32);
    if (lane == 0) density[b * CH + r] = ssum * (1.0f / CH);
  }
}

// ---------------------------------------------------------------------------
// K3: per-batch MLP  scale = sigmoid(relu(density@W1+b1)@W2+b2) + GAMMA
// ---------------------------------------------------------------------------
__global__ __launch_bounds__(256)
void mlp_kernel(const float* __restrict__ density,
                const float* __restrict__ w1, const float* __restrict__ b1,
                const float* __restrict__ w2, const float* __restrict__ b2,
                float* __restrict__ scale) {
  const int b = blockIdx.x;
  const int t = threadIdx.x;
  __shared__ float dens[CH];
  __shared__ float hid[RED];
  dens[t] = density[b * CH + t];
  __syncthreads();
  if (t < RED) {
    float s = b1[t];
#pragma unroll 4
    for (int c = 0; c < CH; ++c) s += dens[c] * w1[c * RED + t];
    hid[t] = fmaxf(s, 0.f);
  }
  __syncthreads();
  float s = b2[t];
#pragma unroll
  for (int h = 0; h < RED; ++h) s += hid[h] * w2[h * CH + t];
  scale[b * CH + t] = 1.f / (1.f + __expf(-s)) + GAMMA;
}

// ---------------------------------------------------------------------------
// K4: out = x * scale[b,c]   (float4 grid-stride, nontemporal stores)
// ---------------------------------------------------------------------------
__global__ __launch_bounds__(256)
void scale_kernel(const f32x4* __restrict__ x, const float* __restrict__ scale,
                  f32x4* __restrict__ out, int n4) {
  const int stride = gridDim.x * blockDim.x;
  for (int i = blockIdx.x * blockDim.x + threadIdx.x; i < n4; i += stride) {
    float s = scale[i >> 10];          // 1024 float4 per (b,c) row
    __builtin_nontemporal_store(x[i] * s, &out[i]);
  }
}

extern "C" void kernel_launch(void* const* d_in, const int* in_sizes, int n_in,
                              void* d_out, int out_size, void* d_ws, size_t ws_size,
                              hipStream_t stream) {
  const float* x  = (const float*)d_in[0];
  const float* w1 = (const float*)d_in[1];
  const float* b1 = (const float*)d_in[2];
  const float* w2 = (const float*)d_in[3];
  const float* b2 = (const float*)d_in[4];
  float* out = (float*)d_out;

  float* gpart   = (float*)d_ws;                       // 4*32*65536 f32 = 33.6 MB
  float* density = gpart + NSPLIT * SLICE_STRIDE;      // 32*256
  float* scale   = density + BATCH * CH;               // 32*256

  gram_sym_kernel<<<dim3(512), dim3(512), 0, stream>>>(x, gpart);
  density_kernel<<<dim3(BATCH * 8), dim3(256), 0, stream>>>(gpart, density);
  mlp_kernel<<<dim3(BATCH), dim3(256), 0, stream>>>(density, w1, b1, w2, b2, scale);

  const int n4 = BATCH * CH * NSP / 4;
  scale_kernel<<<dim3(4096), dim3(256), 0, stream>>>(
      (const f32x4*)x, scale, (f32x4*)out, n4);
}